// Round 1
// baseline (1523.244 us; speedup 1.0000x reference)
//
#include <hip/hip_runtime.h>

typedef short bf16x8 __attribute__((ext_vector_type(8)));
typedef float f32x4 __attribute__((ext_vector_type(4)));
typedef unsigned short u16;

#define NT 4096       // B*T tokens
#define DM 1024       // model dim
#define DF 2048       // ff dim
#define NE 8          // experts
#define NV 32000      // vocab

__device__ __forceinline__ u16 f2bf(float f) {
  unsigned u = __float_as_uint(f);
  u += 0x7fffu + ((u >> 16) & 1u);   // round-nearest-even
  return (u16)(u >> 16);
}

__device__ __forceinline__ void async16(const void* g, void* l) {
  __builtin_amdgcn_global_load_lds(
      (const __attribute__((address_space(1))) void*)g,
      (__attribute__((address_space(3))) void*)l, 16, 0, 0);
}

// ---------------- weight conversion ----------------
__global__ void cvt_bf16_kernel(const float* __restrict__ src, u16* __restrict__ dst, int n4) {
  int i = blockIdx.x * blockDim.x + threadIdx.x;
  int stride = gridDim.x * blockDim.x;
  for (; i < n4; i += stride) {
    float4 v = ((const float4*)src)[i];
    ushort4 o;
    o.x = f2bf(v.x); o.y = f2bf(v.y); o.z = f2bf(v.z); o.w = f2bf(v.w);
    ((ushort4*)dst)[i] = o;
  }
}

// W:[E][R][C] f32  ->  WT:[E][C][R] bf16   (B^T layout for the GEMMs)
__global__ void transpose_cvt_kernel(const float* __restrict__ W, u16* __restrict__ WT, int R, int C) {
  __shared__ float tile[32][33];
  int e = blockIdx.z;
  const float* We = W + (size_t)e * R * C;
  u16* WTe = WT + (size_t)e * R * C;
  int c0 = blockIdx.x * 32, r0 = blockIdx.y * 32;
  int tx = threadIdx.x, ty = threadIdx.y;
  #pragma unroll
  for (int i = 0; i < 32; i += 8)
    tile[ty + i][tx] = We[(size_t)(r0 + ty + i) * C + (c0 + tx)];
  __syncthreads();
  #pragma unroll
  for (int i = 0; i < 32; i += 8)
    WTe[(size_t)(c0 + ty + i) * R + (r0 + tx)] = f2bf(tile[tx][ty + i]);
}

// ---------------- embed + gate + softmax + top2 + routing ----------------
// one block (256 thr) per token
__global__ void embed_gate_kernel(const int* __restrict__ x, const float* __restrict__ embW,
                                  const float* __restrict__ gateW, const float* __restrict__ gateb,
                                  u16* __restrict__ A1, int* __restrict__ dest, float* __restrict__ gatev,
                                  int* __restrict__ cnt, float* __restrict__ topk_out) {
  int n = blockIdx.x, tid = threadIdx.x;
  int row = x[n];
  float4 h4 = ((const float4*)(embW + (size_t)row * DM))[tid];
  float p[NE];
  #pragma unroll
  for (int e = 0; e < NE; ++e) {
    float4 w = ((const float4*)(gateW + e * DM))[tid];
    p[e] = h4.x * w.x + h4.y * w.y + h4.z * w.z + h4.w * w.w;
  }
  #pragma unroll
  for (int off = 32; off > 0; off >>= 1)
    #pragma unroll
    for (int e = 0; e < NE; ++e) p[e] += __shfl_down(p[e], off);

  __shared__ float part[4][NE];
  __shared__ int bc[4];
  int wave = tid >> 6, lane = tid & 63;
  if (lane == 0)
    for (int e = 0; e < NE; ++e) part[wave][e] = p[e];
  __syncthreads();
  if (tid == 0) {
    float l[NE];
    #pragma unroll
    for (int e = 0; e < NE; ++e)
      l[e] = part[0][e] + part[1][e] + part[2][e] + part[3][e] + gateb[e];
    float mx = l[0];
    #pragma unroll
    for (int e = 1; e < NE; ++e) mx = fmaxf(mx, l[e]);
    float pe[NE], s = 0.f;
    #pragma unroll
    for (int e = 0; e < NE; ++e) { pe[e] = expf(l[e] - mx); s += pe[e]; }
    int i1 = 0; float b1v = l[0];
    #pragma unroll
    for (int e = 1; e < NE; ++e) if (l[e] > b1v) { b1v = l[e]; i1 = e; }
    int i2 = -1; float b2v = -1e30f;
    #pragma unroll
    for (int e = 0; e < NE; ++e) if (e != i1 && l[e] > b2v) { b2v = l[e]; i2 = e; }
    float inv = 1.0f / s;
    int s1 = atomicAdd(&cnt[i1], 1);
    int s2 = atomicAdd(&cnt[i2], 1);
    dest[i1 * NT + s1] = n * 2;
    dest[i2 * NT + s2] = n * 2 + 1;
    gatev[i1 * NT + s1] = pe[i1] * inv;
    gatev[i2 * NT + s2] = pe[i2] * inv;
    topk_out[n * 2]     = (float)i1;   // out dtype is float*: indices as floats
    topk_out[n * 2 + 1] = (float)i2;
    bc[0] = i1; bc[1] = s1; bc[2] = i2; bc[3] = s2;
  }
  __syncthreads();
  int e1 = bc[0], s1 = bc[1], e2 = bc[2], s2 = bc[3];
  ushort4 hb;
  hb.x = f2bf(h4.x); hb.y = f2bf(h4.y); hb.z = f2bf(h4.z); hb.w = f2bf(h4.w);
  ((ushort4*)(A1 + ((size_t)e1 * NT + s1) * DM))[tid] = hb;
  ((ushort4*)(A1 + ((size_t)e2 * NT + s2) * DM))[tid] = hb;
}

// ---------------- 128x128 bf16 MFMA GEMM core (m97 structure) ----------------
// A: rows m0..m0+127 stride K (bf16); B: rows n0..n0+127 stride K (B^T, bf16)
template <int K>
__device__ __forceinline__ void gemm_tile(const u16* __restrict__ A, const u16* __restrict__ B,
                                          f32x4 acc[4][4], u16* sA, u16* sB) {
  const int tid = threadIdx.x;
  const u16* gA = A + (size_t)(tid >> 3) * K + (tid & 7) * 8;
  const u16* gB = B + (size_t)(tid >> 3) * K + (tid & 7) * 8;
  u16* dA = sA + tid * 8;   // byte offset tid*16 : wave-uniform base + lane*16
  u16* dB = sB + tid * 8;
  const int lane = tid & 63;
  const int wm = ((tid >> 7) & 1) * 64;
  const int wn = ((tid >> 6) & 1) * 64;
  const int fm = lane & 15;
  const int fq = lane >> 4;
  const int aoff = (wm + fm) * 64 + fq * 8;
  const int boff = (wn + fm) * 64 + fq * 8;

  for (int k0 = 0; k0 < K; k0 += 64) {
    #pragma unroll
    for (int it = 0; it < 4; ++it) {
      async16(gA + (size_t)it * 32 * K + k0, dA + it * 2048);
      async16(gB + (size_t)it * 32 * K + k0, dB + it * 2048);
    }
    __syncthreads();
    #pragma unroll
    for (int ks = 0; ks < 2; ++ks) {
      bf16x8 af[4], bfr[4];
      #pragma unroll
      for (int mt = 0; mt < 4; ++mt)
        af[mt] = *(const bf16x8*)(sA + aoff + mt * 16 * 64 + ks * 32);
      #pragma unroll
      for (int nt = 0; nt < 4; ++nt)
        bfr[nt] = *(const bf16x8*)(sB + boff + nt * 16 * 64 + ks * 32);
      #pragma unroll
      for (int mt = 0; mt < 4; ++mt)
        #pragma unroll
        for (int nt = 0; nt < 4; ++nt)
          acc[mt][nt] = __builtin_amdgcn_mfma_f32_16x16x32_bf16(af[mt], bfr[nt], acc[mt][nt], 0, 0, 0);
    }
    __syncthreads();
  }
}

#define ACC_INIT(acc)                          \
  f32x4 acc[4][4];                             \
  _Pragma("unroll")                            \
  for (int i = 0; i < 4; ++i)                  \
    _Pragma("unroll")                          \
    for (int j = 0; j < 4; ++j) acc[i][j] = (f32x4){0.f, 0.f, 0.f, 0.f};

// expert GEMM1: apack = relu(A1 @ W1T^T + b1), bf16 out
__global__ __launch_bounds__(256) void gemm1_kernel(const u16* __restrict__ A1, const u16* __restrict__ W1T,
                                                    const float* __restrict__ b1, u16* __restrict__ apack,
                                                    const int* __restrict__ cnt) {
  int e = blockIdx.z;
  int m0 = blockIdx.y * 128, n0 = blockIdx.x * 128;
  if (m0 >= cnt[e]) return;
  __shared__ u16 sA[128 * 64], sB[128 * 64];
  ACC_INIT(acc)
  gemm_tile<DM>(A1 + ((size_t)e * NT + m0) * DM, W1T + ((size_t)e * DF + n0) * DM, acc, sA, sB);
  int tid = threadIdx.x, lane = tid & 63;
  int wm = ((tid >> 7) & 1) * 64, wn = ((tid >> 6) & 1) * 64;
  int fm = lane & 15, fq = lane >> 4;
  #pragma unroll
  for (int mt = 0; mt < 4; ++mt)
    #pragma unroll
    for (int nt = 0; nt < 4; ++nt) {
      int col = n0 + wn + nt * 16 + fm;
      float bias = b1[e * DF + col];
      #pragma unroll
      for (int r = 0; r < 4; ++r) {
        int m = m0 + wm + mt * 16 + fq * 4 + r;
        apack[((size_t)e * NT + m) * DF + col] = f2bf(fmaxf(acc[mt][nt][r] + bias, 0.f));
      }
    }
}

// expert GEMM2: ypair[dest[m]] = gate[m] * (apack @ W2T^T + b2), f32 scatter
__global__ __launch_bounds__(256) void gemm2_kernel(const u16* __restrict__ apack, const u16* __restrict__ W2T,
                                                    const float* __restrict__ b2, const int* __restrict__ dest,
                                                    const float* __restrict__ gatev, const int* __restrict__ cnt,
                                                    float* __restrict__ ypair) {
  int e = blockIdx.z;
  int m0 = blockIdx.y * 128, n0 = blockIdx.x * 128;
  int ce = cnt[e];
  if (m0 >= ce) return;
  __shared__ u16 sA[128 * 64], sB[128 * 64];
  ACC_INIT(acc)
  gemm_tile<DF>(apack + ((size_t)e * NT + m0) * DF, W2T + ((size_t)e * DM + n0) * DF, acc, sA, sB);
  int tid = threadIdx.x, lane = tid & 63;
  int wm = ((tid >> 7) & 1) * 64, wn = ((tid >> 6) & 1) * 64;
  int fm = lane & 15, fq = lane >> 4;
  #pragma unroll
  for (int mt = 0; mt < 4; ++mt)
    #pragma unroll
    for (int r = 0; r < 4; ++r) {
      int m = m0 + wm + mt * 16 + fq * 4 + r;
      if (m < ce) {
        int d = dest[e * NT + m];
        float gv = gatev[e * NT + m];
        #pragma unroll
        for (int nt = 0; nt < 4; ++nt) {
          int col = n0 + wn + nt * 16 + fm;
          ypair[(size_t)d * DM + col] = gv * (acc[mt][nt][r] + b2[e * DM + col]);
        }
      }
    }
}

// combine two expert contributions + LayerNorm -> bf16
__global__ void combine_ln_kernel(const float* __restrict__ ypair, const float* __restrict__ g,
                                  const float* __restrict__ b, u16* __restrict__ yn) {
  int n = blockIdx.x, tid = threadIdx.x;
  float4 va = ((const float4*)(ypair + (size_t)(2 * n) * DM))[tid];
  float4 vb = ((const float4*)(ypair + (size_t)(2 * n + 1) * DM))[tid];
  float4 v;
  v.x = va.x + vb.x; v.y = va.y + vb.y; v.z = va.z + vb.z; v.w = va.w + vb.w;
  float s = v.x + v.y + v.z + v.w;
  float q = v.x * v.x + v.y * v.y + v.z * v.z + v.w * v.w;
  #pragma unroll
  for (int off = 32; off > 0; off >>= 1) {
    s += __shfl_down(s, off);
    q += __shfl_down(q, off);
  }
  __shared__ float red[4][2];
  __shared__ float mr[2];
  int wave = tid >> 6, lane = tid & 63;
  if (lane == 0) { red[wave][0] = s; red[wave][1] = q; }
  __syncthreads();
  if (tid == 0) {
    float S = red[0][0] + red[1][0] + red[2][0] + red[3][0];
    float Q = red[0][1] + red[1][1] + red[2][1] + red[3][1];
    float mu = S * (1.0f / DM);
    float var = Q * (1.0f / DM) - mu * mu;
    mr[0] = mu;
    mr[1] = rsqrtf(var + 1e-5f);
  }
  __syncthreads();
  float mu = mr[0], r = mr[1];
  float4 gg = ((const float4*)g)[tid];
  float4 bb = ((const float4*)b)[tid];
  ushort4 o;
  o.x = f2bf((v.x - mu) * r * gg.x + bb.x);
  o.y = f2bf((v.y - mu) * r * gg.y + bb.y);
  o.z = f2bf((v.z - mu) * r * gg.z + bb.z);
  o.w = f2bf((v.w - mu) * r * gg.w + bb.w);
  ((ushort4*)(yn + (size_t)n * DM))[tid] = o;
}

// head GEMM: logits = yn @ headW^T + head_b, f32 out.
// T1: bijective XCD-chunk swizzle (HW dispatches flat id round-robin across the
// 8 XCDs; remap so each XCD owns a contiguous chunk of tiles, m fast within the
// chunk -> the XCD's 32 CUs share one 256KB B-panel in its private L2).
// C-writes are non-temporal: 512MB write-once stream must not evict B from L2/L3.
__global__ __launch_bounds__(256) void head_kernel(const u16* __restrict__ yn, const u16* __restrict__ hw,
                                                   const float* __restrict__ hb, float* __restrict__ out) {
  const int nwg = gridDim.x * gridDim.y;            // 32*250 = 8000
  int flat = blockIdx.y * gridDim.x + blockIdx.x;   // HW dispatch order (x fast)
  const int nx = 8;                                 // XCDs
  int q = nwg / nx, rr = nwg % nx;
  int xcd = flat % nx, pos = flat / nx;
  int swz = (xcd < rr ? xcd * (q + 1) : rr * (q + 1) + (xcd - rr) * q) + pos;
  int m0 = (swz % gridDim.x) * 128;                 // m fast within chunk
  int n0 = (swz / gridDim.x) * 128;

  __shared__ u16 sA[128 * 64], sB[128 * 64];
  ACC_INIT(acc)
  gemm_tile<DM>(yn + (size_t)m0 * DM, hw + (size_t)n0 * DM, acc, sA, sB);
  int tid = threadIdx.x, lane = tid & 63;
  int wm = ((tid >> 7) & 1) * 64, wn = ((tid >> 6) & 1) * 64;
  int fm = lane & 15, fq = lane >> 4;
  #pragma unroll
  for (int mt = 0; mt < 4; ++mt)
    #pragma unroll
    for (int nt = 0; nt < 4; ++nt) {
      int col = n0 + wn + nt * 16 + fm;
      float bias = hb[col];
      #pragma unroll
      for (int r = 0; r < 4; ++r) {
        int m = m0 + wm + mt * 16 + fq * 4 + r;
        __builtin_nontemporal_store(acc[mt][nt][r] + bias, &out[(size_t)m * NV + col]);
      }
    }
}

extern "C" void kernel_launch(void* const* d_in, const int* in_sizes, int n_in,
                              void* d_out, int out_size, void* d_ws, size_t ws_size,
                              hipStream_t stream) {
  const int*   x     = (const int*)  d_in[0];
  const float* embW  = (const float*)d_in[1];
  const float* gateW = (const float*)d_in[2];
  const float* gateb = (const float*)d_in[3];
  const float* W1    = (const float*)d_in[4];
  const float* b1    = (const float*)d_in[5];
  const float* W2    = (const float*)d_in[6];
  const float* b2    = (const float*)d_in[7];
  const float* lng   = (const float*)d_in[8];
  const float* lnb   = (const float*)d_in[9];
  const float* headW = (const float*)d_in[10];
  const float* headb = (const float*)d_in[11];
  float* out = (float*)d_out;

  // scratch inside d_out's logits region (dead before head_kernel writes it)
  char* ob = (char*)d_out;
  u16*   A1    = (u16*)  (ob + 0);            // 64 MiB  bf16 [E][NT][DM]
  u16*   APACK = (u16*)  (ob + 67108864);     // 128 MiB bf16 [E][NT][DF]
  float* YPAIR = (float*)(ob + 201326592);    // 32 MiB  f32  [2*NT][DM]
  u16*   W1T   = (u16*)  (ob + 234881024);    // 32 MiB  bf16 [E][DF][DM]
  u16*   W2T   = (u16*)  (ob + 268435456);    // 32 MiB  bf16 [E][DM][DF]
  float* TOPK  = (float*)(ob + 524288000);    // after logits: [NT][2]

  char* wb = (char*)d_ws;
  u16*   HWB  = (u16*)  (wb);                 // 65.5 MB bf16 [NV][DM]
  u16*   YN   = (u16*)  (wb + 65536000);      // 8.4 MB  bf16 [NT][DM]
  int*   DEST = (int*)  (wb + 73924608);
  float* GV   = (float*)(wb + 74055680);
  int*   CNT  = (int*)  (wb + 74186752);

  hipMemsetAsync(CNT, 0, NE * sizeof(int), stream);
  cvt_bf16_kernel<<<4096, 256, 0, stream>>>(headW, HWB, NV * DM / 4);
  transpose_cvt_kernel<<<dim3(DF / 32, DM / 32, NE), dim3(32, 8), 0, stream>>>(W1, W1T, DM, DF);
  transpose_cvt_kernel<<<dim3(DM / 32, DF / 32, NE), dim3(32, 8), 0, stream>>>(W2, W2T, DF, DM);
  embed_gate_kernel<<<NT, 256, 0, stream>>>(x, embW, gateW, gateb, A1, DEST, GV, CNT, TOPK);
  gemm1_kernel<<<dim3(DF / 128, NT / 128, NE), 256, 0, stream>>>(A1, W1T, b1, APACK, CNT);
  gemm2_kernel<<<dim3(DM / 128, NT / 128, NE), 256, 0, stream>>>(APACK, W2T, b2, DEST, GV, CNT, YPAIR);
  combine_ln_kernel<<<NT, 256, 0, stream>>>(YPAIR, lng, lnb, YN);
  head_kernel<<<dim3(NT / 128, NV / 128), 256, 0, stream>>>(YN, HWB, headb, out);
}

// Round 2
// 1428.429 us; speedup vs baseline: 1.0664x; 1.0664x over previous
//
#include <hip/hip_runtime.h>

typedef short bf16x8 __attribute__((ext_vector_type(8)));
typedef float f32x4 __attribute__((ext_vector_type(4)));
typedef unsigned short u16;

#define NT 4096       // B*T tokens
#define DM 1024       // model dim
#define DF 2048       // ff dim
#define NE 8          // experts
#define NV 32000      // vocab

__device__ __forceinline__ u16 f2bf(float f) {
  unsigned u = __float_as_uint(f);
  u += 0x7fffu + ((u >> 16) & 1u);   // round-nearest-even
  return (u16)(u >> 16);
}

__device__ __forceinline__ void async16(const void* g, void* l) {
  __builtin_amdgcn_global_load_lds(
      (const __attribute__((address_space(1))) void*)g,
      (__attribute__((address_space(3))) void*)l, 16, 0, 0);
}

// ---------------- weight conversion ----------------
__global__ void cvt_bf16_kernel(const float* __restrict__ src, u16* __restrict__ dst, int n4) {
  int i = blockIdx.x * blockDim.x + threadIdx.x;
  int stride = gridDim.x * blockDim.x;
  for (; i < n4; i += stride) {
    float4 v = ((const float4*)src)[i];
    ushort4 o;
    o.x = f2bf(v.x); o.y = f2bf(v.y); o.z = f2bf(v.z); o.w = f2bf(v.w);
    ((ushort4*)dst)[i] = o;
  }
}

// W:[E][R][C] f32  ->  WT:[E][C][R] bf16   (B^T layout for the GEMMs)
__global__ void transpose_cvt_kernel(const float* __restrict__ W, u16* __restrict__ WT, int R, int C) {
  __shared__ float tile[32][33];
  int e = blockIdx.z;
  const float* We = W + (size_t)e * R * C;
  u16* WTe = WT + (size_t)e * R * C;
  int c0 = blockIdx.x * 32, r0 = blockIdx.y * 32;
  int tx = threadIdx.x, ty = threadIdx.y;
  #pragma unroll
  for (int i = 0; i < 32; i += 8)
    tile[ty + i][tx] = We[(size_t)(r0 + ty + i) * C + (c0 + tx)];
  __syncthreads();
  #pragma unroll
  for (int i = 0; i < 32; i += 8)
    WTe[(size_t)(c0 + ty + i) * R + (r0 + tx)] = f2bf(tile[tx][ty + i]);
}

// ---------------- embed + gate + softmax + top2 + routing ----------------
__global__ void embed_gate_kernel(const int* __restrict__ x, const float* __restrict__ embW,
                                  const float* __restrict__ gateW, const float* __restrict__ gateb,
                                  u16* __restrict__ A1, int* __restrict__ dest, float* __restrict__ gatev,
                                  int* __restrict__ cnt, float* __restrict__ topk_out) {
  int n = blockIdx.x, tid = threadIdx.x;
  int row = x[n];
  float4 h4 = ((const float4*)(embW + (size_t)row * DM))[tid];
  float p[NE];
  #pragma unroll
  for (int e = 0; e < NE; ++e) {
    float4 w = ((const float4*)(gateW + e * DM))[tid];
    p[e] = h4.x * w.x + h4.y * w.y + h4.z * w.z + h4.w * w.w;
  }
  #pragma unroll
  for (int off = 32; off > 0; off >>= 1)
    #pragma unroll
    for (int e = 0; e < NE; ++e) p[e] += __shfl_down(p[e], off);

  __shared__ float part[4][NE];
  __shared__ int bc[4];
  int wave = tid >> 6, lane = tid & 63;
  if (lane == 0)
    for (int e = 0; e < NE; ++e) part[wave][e] = p[e];
  __syncthreads();
  if (tid == 0) {
    float l[NE];
    #pragma unroll
    for (int e = 0; e < NE; ++e)
      l[e] = part[0][e] + part[1][e] + part[2][e] + part[3][e] + gateb[e];
    float mx = l[0];
    #pragma unroll
    for (int e = 1; e < NE; ++e) mx = fmaxf(mx, l[e]);
    float pe[NE], s = 0.f;
    #pragma unroll
    for (int e = 0; e < NE; ++e) { pe[e] = expf(l[e] - mx); s += pe[e]; }
    int i1 = 0; float b1v = l[0];
    #pragma unroll
    for (int e = 1; e < NE; ++e) if (l[e] > b1v) { b1v = l[e]; i1 = e; }
    int i2 = -1; float b2v = -1e30f;
    #pragma unroll
    for (int e = 0; e < NE; ++e) if (e != i1 && l[e] > b2v) { b2v = l[e]; i2 = e; }
    float inv = 1.0f / s;
    int s1 = atomicAdd(&cnt[i1], 1);
    int s2 = atomicAdd(&cnt[i2], 1);
    dest[i1 * NT + s1] = n * 2;
    dest[i2 * NT + s2] = n * 2 + 1;
    gatev[i1 * NT + s1] = pe[i1] * inv;
    gatev[i2 * NT + s2] = pe[i2] * inv;
    topk_out[n * 2]     = (float)i1;
    topk_out[n * 2 + 1] = (float)i2;
    bc[0] = i1; bc[1] = s1; bc[2] = i2; bc[3] = s2;
  }
  __syncthreads();
  int e1 = bc[0], s1 = bc[1], e2 = bc[2], s2 = bc[3];
  ushort4 hb;
  hb.x = f2bf(h4.x); hb.y = f2bf(h4.y); hb.z = f2bf(h4.z); hb.w = f2bf(h4.w);
  ((ushort4*)(A1 + ((size_t)e1 * NT + s1) * DM))[tid] = hb;
  ((ushort4*)(A1 + ((size_t)e2 * NT + s2) * DM))[tid] = hb;
}

// ---------------- 128x128 bf16 MFMA GEMM core (m97 structure) ----------------
template <int K>
__device__ __forceinline__ void gemm_tile(const u16* __restrict__ A, const u16* __restrict__ B,
                                          f32x4 acc[4][4], u16* sA, u16* sB) {
  const int tid = threadIdx.x;
  const u16* gA = A + (size_t)(tid >> 3) * K + (tid & 7) * 8;
  const u16* gB = B + (size_t)(tid >> 3) * K + (tid & 7) * 8;
  u16* dA = sA + tid * 8;
  u16* dB = sB + tid * 8;
  const int lane = tid & 63;
  const int wm = ((tid >> 7) & 1) * 64;
  const int wn = ((tid >> 6) & 1) * 64;
  const int fm = lane & 15;
  const int fq = lane >> 4;
  const int aoff = (wm + fm) * 64 + fq * 8;
  const int boff = (wn + fm) * 64 + fq * 8;

  for (int k0 = 0; k0 < K; k0 += 64) {
    #pragma unroll
    for (int it = 0; it < 4; ++it) {
      async16(gA + (size_t)it * 32 * K + k0, dA + it * 2048);
      async16(gB + (size_t)it * 32 * K + k0, dB + it * 2048);
    }
    __syncthreads();
    #pragma unroll
    for (int ks = 0; ks < 2; ++ks) {
      bf16x8 af[4], bfr[4];
      #pragma unroll
      for (int mt = 0; mt < 4; ++mt)
        af[mt] = *(const bf16x8*)(sA + aoff + mt * 16 * 64 + ks * 32);
      #pragma unroll
      for (int nt = 0; nt < 4; ++nt)
        bfr[nt] = *(const bf16x8*)(sB + boff + nt * 16 * 64 + ks * 32);
      #pragma unroll
      for (int mt = 0; mt < 4; ++mt)
        #pragma unroll
        for (int nt = 0; nt < 4; ++nt)
          acc[mt][nt] = __builtin_amdgcn_mfma_f32_16x16x32_bf16(af[mt], bfr[nt], acc[mt][nt], 0, 0, 0);
    }
    __syncthreads();
  }
}

#define ACC_INIT(acc)                          \
  f32x4 acc[4][4];                             \
  _Pragma("unroll")                            \
  for (int i = 0; i < 4; ++i)                  \
    _Pragma("unroll")                          \
    for (int j = 0; j < 4; ++j) acc[i][j] = (f32x4){0.f, 0.f, 0.f, 0.f};

// expert GEMM1: apack = relu(A1 @ W1T^T + b1), bf16 out
__global__ __launch_bounds__(256) void gemm1_kernel(const u16* __restrict__ A1, const u16* __restrict__ W1T,
                                                    const float* __restrict__ b1, u16* __restrict__ apack,
                                                    const int* __restrict__ cnt) {
  int e = blockIdx.z;
  int m0 = blockIdx.y * 128, n0 = blockIdx.x * 128;
  if (m0 >= cnt[e]) return;
  __shared__ u16 sA[128 * 64], sB[128 * 64];
  ACC_INIT(acc)
  gemm_tile<DM>(A1 + ((size_t)e * NT + m0) * DM, W1T + ((size_t)e * DF + n0) * DM, acc, sA, sB);
  int tid = threadIdx.x, lane = tid & 63;
  int wm = ((tid >> 7) & 1) * 64, wn = ((tid >> 6) & 1) * 64;
  int fm = lane & 15, fq = lane >> 4;
  #pragma unroll
  for (int mt = 0; mt < 4; ++mt)
    #pragma unroll
    for (int nt = 0; nt < 4; ++nt) {
      int col = n0 + wn + nt * 16 + fm;
      float bias = b1[e * DF + col];
      #pragma unroll
      for (int r = 0; r < 4; ++r) {
        int m = m0 + wm + mt * 16 + fq * 4 + r;
        apack[((size_t)e * NT + m) * DF + col] = f2bf(fmaxf(acc[mt][nt][r] + bias, 0.f));
      }
    }
}

// expert GEMM2: ypair[dest[m]] = gate[m] * (apack @ W2T^T + b2), f32 scatter
__global__ __launch_bounds__(256) void gemm2_kernel(const u16* __restrict__ apack, const u16* __restrict__ W2T,
                                                    const float* __restrict__ b2, const int* __restrict__ dest,
                                                    const float* __restrict__ gatev, const int* __restrict__ cnt,
                                                    float* __restrict__ ypair) {
  int e = blockIdx.z;
  int m0 = blockIdx.y * 128, n0 = blockIdx.x * 128;
  int ce = cnt[e];
  if (m0 >= ce) return;
  __shared__ u16 sA[128 * 64], sB[128 * 64];
  ACC_INIT(acc)
  gemm_tile<DF>(apack + ((size_t)e * NT + m0) * DF, W2T + ((size_t)e * DM + n0) * DF, acc, sA, sB);
  int tid = threadIdx.x, lane = tid & 63;
  int wm = ((tid >> 7) & 1) * 64, wn = ((tid >> 6) & 1) * 64;
  int fm = lane & 15, fq = lane >> 4;
  #pragma unroll
  for (int mt = 0; mt < 4; ++mt)
    #pragma unroll
    for (int r = 0; r < 4; ++r) {
      int m = m0 + wm + mt * 16 + fq * 4 + r;
      if (m < ce) {
        int d = dest[e * NT + m];
        float gv = gatev[e * NT + m];
        #pragma unroll
        for (int nt = 0; nt < 4; ++nt) {
          int col = n0 + wn + nt * 16 + fm;
          ypair[(size_t)d * DM + col] = gv * (acc[mt][nt][r] + b2[e * DM + col]);
        }
      }
    }
}

// combine two expert contributions + LayerNorm -> bf16
__global__ void combine_ln_kernel(const float* __restrict__ ypair, const float* __restrict__ g,
                                  const float* __restrict__ b, u16* __restrict__ yn) {
  int n = blockIdx.x, tid = threadIdx.x;
  float4 va = ((const float4*)(ypair + (size_t)(2 * n) * DM))[tid];
  float4 vb = ((const float4*)(ypair + (size_t)(2 * n + 1) * DM))[tid];
  float4 v;
  v.x = va.x + vb.x; v.y = va.y + vb.y; v.z = va.z + vb.z; v.w = va.w + vb.w;
  float s = v.x + v.y + v.z + v.w;
  float q = v.x * v.x + v.y * v.y + v.z * v.z + v.w * v.w;
  #pragma unroll
  for (int off = 32; off > 0; off >>= 1) {
    s += __shfl_down(s, off);
    q += __shfl_down(q, off);
  }
  __shared__ float red[4][2];
  __shared__ float mr[2];
  int wave = tid >> 6, lane = tid & 63;
  if (lane == 0) { red[wave][0] = s; red[wave][1] = q; }
  __syncthreads();
  if (tid == 0) {
    float S = red[0][0] + red[1][0] + red[2][0] + red[3][0];
    float Q = red[0][1] + red[1][1] + red[2][1] + red[3][1];
    float mu = S * (1.0f / DM);
    float var = Q * (1.0f / DM) - mu * mu;
    mr[0] = mu;
    mr[1] = rsqrtf(var + 1e-5f);
  }
  __syncthreads();
  float mu = mr[0], r = mr[1];
  float4 gg = ((const float4*)g)[tid];
  float4 bb = ((const float4*)b)[tid];
  ushort4 o;
  o.x = f2bf((v.x - mu) * r * gg.x + bb.x);
  o.y = f2bf((v.y - mu) * r * gg.y + bb.y);
  o.z = f2bf((v.z - mu) * r * gg.z + bb.z);
  o.w = f2bf((v.w - mu) * r * gg.w + bb.w);
  ((ushort4*)(yn + (size_t)n * DM))[tid] = o;
}

// ---------------- head GEMM: 256x256 tile, BK=64, 8 waves, counted-vmcnt ----------------
// logits = yn @ headW^T + head_b, f32 out.  M=4096 (16 tiles) x N=32000 (125 tiles), K=1024.
// Double-buffered LDS (128 KiB), raw s_barrier + s_waitcnt vmcnt(8): next tile's 8
// global_load_lds stay in flight across the barrier (T4) instead of the __syncthreads
// vmcnt(0) drain.  Normal cached stores (non-temporal stores regressed: +580MB RMW fetch).
// XCD swizzle: each XCD owns 250 contiguous tiles, m fast -> B-panel L2 locality.
__global__ __launch_bounds__(512, 2) void head_kernel(const u16* __restrict__ yn, const u16* __restrict__ hw,
                                                      const float* __restrict__ hb, float* __restrict__ out) {
  // tile decode with bijective XCD chunking (nwg = 16*125 = 2000, 250 per XCD)
  int flat = blockIdx.y * gridDim.x + blockIdx.x;   // HW order, x fast
  int xcd = flat & 7, pos = flat >> 3;
  int swz = xcd * 250 + pos;
  int m0 = (swz & 15) * 256;        // m fast within chunk
  int n0 = (swz >> 4) * 256;

  __shared__ u16 sA0[256 * 64], sB0[256 * 64], sA1[256 * 64], sB1[256 * 64];  // 128 KiB

  const int tid = threadIdx.x;
  const int lane = tid & 63;
  const int wid = tid >> 6;                 // 8 waves: 2 (M) x 4 (N)
  const int wm = (wid >> 2) * 128;
  const int wn = (wid & 3) * 64;
  const int fm = lane & 15;
  const int fq = lane >> 4;

  // staging source: thread loads rows (tid>>3)+64*i, cols (tid&7)*8 .. +8, of the k-slab
  const u16* gA = yn + (size_t)(m0 + (tid >> 3)) * DM + (tid & 7) * 8;
  const u16* gB = hw + (size_t)(n0 + (tid >> 3)) * DM + (tid & 7) * 8;
  const int ldst = tid * 8;                 // element offset within each 64-row round

  f32x4 acc[8][4];
  #pragma unroll
  for (int i = 0; i < 8; ++i)
    #pragma unroll
    for (int j = 0; j < 4; ++j) acc[i][j] = (f32x4){0.f, 0.f, 0.f, 0.f};

  u16 *pa = sA0, *pb = sB0, *qa = sA1, *qb = sB1;

  // prologue: stage tile 0 into buf0
  #pragma unroll
  for (int i = 0; i < 4; ++i) {
    async16(gA + (size_t)i * 64 * DM, pa + i * 4096 + ldst);
    async16(gB + (size_t)i * 64 * DM, pb + i * 4096 + ldst);
  }

  const int NK = DM / 64;   // 16
  for (int t = 0; t < NK; ++t) {
    if (t < NK - 1) {
      int k0 = (t + 1) * 64;
      #pragma unroll
      for (int i = 0; i < 4; ++i) {
        async16(gA + (size_t)i * 64 * DM + k0, qa + i * 4096 + ldst);
        async16(gB + (size_t)i * 64 * DM + k0, qb + i * 4096 + ldst);
      }
      asm volatile("s_waitcnt vmcnt(8)" ::: "memory");  // tile t landed; t+1's 8 in flight
    } else {
      asm volatile("s_waitcnt vmcnt(0)" ::: "memory");
    }
    __builtin_amdgcn_sched_barrier(0);
    __builtin_amdgcn_s_barrier();           // all waves' tile-t loads landed
    __builtin_amdgcn_sched_barrier(0);

    #pragma unroll
    for (int ks = 0; ks < 2; ++ks) {
      bf16x8 bfr[4];
      #pragma unroll
      for (int nt = 0; nt < 4; ++nt)
        bfr[nt] = *(const bf16x8*)(pb + (wn + nt * 16 + fm) * 64 + ks * 32 + fq * 8);
      #pragma unroll
      for (int mt = 0; mt < 8; ++mt) {
        bf16x8 af = *(const bf16x8*)(pa + (wm + mt * 16 + fm) * 64 + ks * 32 + fq * 8);
        #pragma unroll
        for (int nt = 0; nt < 4; ++nt)
          acc[mt][nt] = __builtin_amdgcn_mfma_f32_16x16x32_bf16(af, bfr[nt], acc[mt][nt], 0, 0, 0);
      }
    }

    __builtin_amdgcn_sched_barrier(0);
    __builtin_amdgcn_s_barrier();           // tile t fully consumed -> its buffer reusable
    __builtin_amdgcn_sched_barrier(0);

    u16* tmp;
    tmp = pa; pa = qa; qa = tmp;
    tmp = pb; pb = qb; qb = tmp;
  }

  // epilogue: normal cached stores
  #pragma unroll
  for (int mt = 0; mt < 8; ++mt)
    #pragma unroll
    for (int nt = 0; nt < 4; ++nt) {
      int col = n0 + wn + nt * 16 + fm;
      float bias = hb[col];
      #pragma unroll
      for (int r = 0; r < 4; ++r) {
        int m = m0 + wm + mt * 16 + fq * 4 + r;
        out[(size_t)m * NV + col] = acc[mt][nt][r] + bias;
      }
    }
}

extern "C" void kernel_launch(void* const* d_in, const int* in_sizes, int n_in,
                              void* d_out, int out_size, void* d_ws, size_t ws_size,
                              hipStream_t stream) {
  const int*   x     = (const int*)  d_in[0];
  const float* embW  = (const float*)d_in[1];
  const float* gateW = (const float*)d_in[2];
  const float* gateb = (const float*)d_in[3];
  const float* W1    = (const float*)d_in[4];
  const float* b1    = (const float*)d_in[5];
  const float* W2    = (const float*)d_in[6];
  const float* b2    = (const float*)d_in[7];
  const float* lng   = (const float*)d_in[8];
  const float* lnb   = (const float*)d_in[9];
  const float* headW = (const float*)d_in[10];
  const float* headb = (const float*)d_in[11];
  float* out = (float*)d_out;

  // scratch inside d_out's logits region (dead before head_kernel writes it)
  char* ob = (char*)d_out;
  u16*   A1    = (u16*)  (ob + 0);            // 64 MiB  bf16 [E][NT][DM]
  u16*   APACK = (u16*)  (ob + 67108864);     // 128 MiB bf16 [E][NT][DF]
  float* YPAIR = (float*)(ob + 201326592);    // 32 MiB  f32  [2*NT][DM]
  u16*   W1T   = (u16*)  (ob + 234881024);    // 32 MiB  bf16 [E][DF][DM]
  u16*   W2T   = (u16*)  (ob + 268435456);    // 32 MiB  bf16 [E][DM][DF]
  float* TOPK  = (float*)(ob + 524288000);    // after logits: [NT][2]

  char* wb = (char*)d_ws;
  u16*   HWB  = (u16*)  (wb);                 // 65.5 MB bf16 [NV][DM]
  u16*   YN   = (u16*)  (wb + 65536000);      // 8.4 MB  bf16 [NT][DM]
  int*   DEST = (int*)  (wb + 73924608);
  float* GV   = (float*)(wb + 74055680);
  int*   CNT  = (int*)  (wb + 74186752);

  hipMemsetAsync(CNT, 0, NE * sizeof(int), stream);
  cvt_bf16_kernel<<<4096, 256, 0, stream>>>(headW, HWB, NV * DM / 4);
  transpose_cvt_kernel<<<dim3(DF / 32, DM / 32, NE), dim3(32, 8), 0, stream>>>(W1, W1T, DM, DF);
  transpose_cvt_kernel<<<dim3(DM / 32, DF / 32, NE), dim3(32, 8), 0, stream>>>(W2, W2T, DF, DM);
  embed_gate_kernel<<<NT, 256, 0, stream>>>(x, embW, gateW, gateb, A1, DEST, GV, CNT, TOPK);
  gemm1_kernel<<<dim3(DF / 128, NT / 128, NE), 256, 0, stream>>>(A1, W1T, b1, APACK, CNT);
  gemm2_kernel<<<dim3(DM / 128, NT / 128, NE), 256, 0, stream>>>(APACK, W2T, b2, DEST, GV, CNT, YPAIR);
  combine_ln_kernel<<<NT, 256, 0, stream>>>(YPAIR, lng, lnb, YN);
  head_kernel<<<dim3(16, 125), 512, 0, stream>>>(YN, HWB, headb, out);
}